// Round 5
// baseline (561.694 us; speedup 1.0000x reference)
//
#include <hip/hip_runtime.h>
#include <math.h>

#define N_NODES 100000
#define N_EDGES 1600000
#define IN_DIM 512
#define OUT_DIM 64
#define NB 1024                    // sort buckets (dst>>7)
#define NPB 128                    // partition blocks
#define CHUNK (N_EDGES / NPB)      // 12500 edges per partition block (exact)
#define N_BUCKETS_USED 782         // ceil(100000/128)
#define N_TILES (N_NODES / 16)     // 6250 exact

typedef __attribute__((ext_vector_type(8))) short short8;
typedef __attribute__((ext_vector_type(4))) float float4v;

__device__ __forceinline__ unsigned short f2bf(float f) {   // RNE fp32->bf16
    unsigned int u = __float_as_uint(f);
    u += 0x7fffu + ((u >> 16) & 1u);
    return (unsigned short)(u >> 16);
}
__device__ __forceinline__ float bf2f(unsigned short s) {
    return __uint_as_float(((unsigned int)s) << 16);
}

// ---------------- pass 1: per-block bucket histogram (layout [bucket][block]) ----
__global__ __launch_bounds__(256) void k_hist1(const int* __restrict__ dst,
                                               int* __restrict__ blockHist) {
    __shared__ int hist[NB];
    const int t = threadIdx.x, b = blockIdx.x;
    for (int k = t; k < NB; k += 256) hist[k] = 0;
    __syncthreads();
    const int e0 = b * CHUNK;
    for (int i = t; i < CHUNK; i += 256)
        atomicAdd(&hist[dst[e0 + i] >> 7], 1);
    __syncthreads();
    for (int k = t; k < NB; k += 256) blockHist[k * NPB + b] = hist[k];
}

// ---------------- pass 2: parallel — thread t owns bucket t ----------------
__global__ __launch_bounds__(1024) void k_offsets(const int* __restrict__ blockHist,  // [NB][NPB]
                                                  int* __restrict__ blockStart,        // [NB][NPB]
                                                  int* __restrict__ bucketBase) {      // [NB+1]
    __shared__ int wsum[16];
    const int t = threadIdx.x, lane = t & 63, w = t >> 6;
    const int4* row = (const int4*)&blockHist[t * NPB];
    int s = 0;
#pragma unroll
    for (int i = 0; i < NPB / 4; ++i) {
        int4 v = row[i];
        s += v.x + v.y + v.z + v.w;
    }
    // block-wide exclusive scan of s over 1024 threads
    int incl = s;
#pragma unroll
    for (int off = 1; off < 64; off <<= 1) {
        int u = __shfl_up(incl, off, 64);
        if (lane >= off) incl += u;
    }
    if (lane == 63) wsum[w] = incl;
    __syncthreads();
    int woff = 0;
#pragma unroll
    for (int k = 0; k < 16; ++k) if (k < w) woff += wsum[k];
    int excl = woff + incl - s;
    bucketBase[t] = excl;
    if (t == 1023) bucketBase[NB] = excl + s;   // == N_EDGES
    // blockStart row: running prefix over the 128 partition blocks (contiguous int4)
    int run = excl;
    int4* brow = (int4*)&blockStart[t * NPB];
#pragma unroll
    for (int i = 0; i < NPB / 4; ++i) {
        int4 v = row[i];
        int4 o;
        o.x = run;
        o.y = run + v.x;
        o.z = o.y + v.y;
        o.w = o.z + v.z;
        run = o.w + v.w;
        brow[i] = o;
    }
}

// ---------------- pass 3: partition edges into buckets (packed codes) ----------------
__global__ __launch_bounds__(256) void k_partition(const int* __restrict__ dst,
                                                   const int* __restrict__ src,
                                                   const int* __restrict__ blockStart,
                                                   int* __restrict__ parts) {
    __shared__ int cursor[NB];
    const int t = threadIdx.x, b = blockIdx.x;
    for (int k = t; k < NB; k += 256) cursor[k] = blockStart[k * NPB + b];
    __syncthreads();
    const int e0 = b * CHUNK;
    for (int i = t; i < CHUNK; i += 256) {
        int d = dst[e0 + i];
        int s = src[e0 + i];
        int k = d >> 7;
        int pos = atomicAdd(&cursor[k], 1);          // LDS atomic (fast)
        parts[pos] = ((d & 127) << 17) | s;           // src < 2^17
    }
}

// ---------------- pass 4: per-bucket counting sort -> deg, row_ptr, csr ----------------
__global__ __launch_bounds__(256) void k_bucket(const int* __restrict__ parts,
                                                const int* __restrict__ bucketBase,
                                                int* __restrict__ degi,
                                                int* __restrict__ row_ptr,
                                                int* __restrict__ csr) {
    __shared__ int cnt[128];
    __shared__ int cur[128];
    __shared__ int wtot[2];
    const int t = threadIdx.x, k = blockIdx.x;
    const int base = bucketBase[k];
    const int n    = bucketBase[k + 1] - base;
    if (t < 128) cnt[t] = 0;
    __syncthreads();
    for (int i = t; i < n; i += 256)
        atomicAdd(&cnt[parts[base + i] >> 17], 1);
    __syncthreads();
    int incl = 0, v = 0;
    if (t < 128) {
        int lane = t & 63;
        v = cnt[t];
        incl = v;
#pragma unroll
        for (int off = 1; off < 64; off <<= 1) {
            int u = __shfl_up(incl, off, 64);
            if (lane >= off) incl += u;
        }
        if (lane == 63) wtot[t >> 6] = incl;
    }
    __syncthreads();
    if (t < 128) {
        int excl = incl - v + ((t >> 6) ? wtot[0] : 0);
        cur[t] = excl;
        int node = k * 128 + t;
        if (node < N_NODES) {
            degi[node]    = v;
            row_ptr[node] = base + excl;
        }
    }
    __syncthreads();
    for (int i = t; i < n; i += 256) {
        int code = parts[base + i];
        int nl = code >> 17, s = code & 0x1FFFF;
        int pos = atomicAdd(&cur[nl], 1);            // LDS atomic
        csr[base + pos] = s;                         // contiguous ~8KB region
    }
}

// ---------------- W swizzle: fp32 [512][64] -> bf16 B-fragment order ----------------
__global__ __launch_bounds__(256) void k_wswz(const float* __restrict__ W,
                                              unsigned short* __restrict__ Wswz) {
    int t = blockIdx.x * 256 + threadIdx.x;
    if (t < IN_DIM * OUT_DIM) {
        int k = t >> 6, n = t & 63;
        int kt = k >> 5, kin = k & 31;
        int quad = kin >> 3, j = kin & 7;
        int ct = n >> 4, l16 = n & 15;
        int lane = quad * 16 + l16;
        Wswz[(((kt * 4 + ct) * 64 + lane) * 8) + j] = f2bf(W[t]);
    }
}

// ---------------- h = dinv * (x @ W), bf16 MFMA, streaming ----------------
// 512 thr = 8 waves/block; LDS 64KB -> 2 blocks/CU = 16 waves/CU (50% occ).
// a[] double-buffered in 4-kt chunks to keep VGPR <= 128.
__global__ __launch_bounds__(512, 4) void k_gemm(const float* __restrict__ x,
                                                 const unsigned short* __restrict__ Wswz,
                                                 const int* __restrict__ degi,
                                                 unsigned short* __restrict__ h) {
    __shared__ short8 Wlds[64][64];   // 64 KB
    const int t = threadIdx.x;
    {
        const float4v* s = (const float4v*)Wswz;
        float4v* d = (float4v*)Wlds;
        for (int i = t; i < 4096; i += 512) d[i] = s[i];
    }
    __syncthreads();

    const int lane = t & 63;
    const int quad = lane >> 4, l16 = lane & 15;
    const int gw = blockIdx.x * 8 + (t >> 6);
    const int nw = gridDim.x * 8;

    for (int tile = gw; tile < N_TILES; tile += nw) {
        const int r0 = tile * 16;
        const float* xrow = x + (size_t)(r0 + l16) * IN_DIM + quad * 8;
        float4v a[2][8];
#pragma unroll
        for (int j = 0; j < 4; ++j) {               // chunk 0: kt 0..3
            a[0][2 * j]     = *(const float4v*)(xrow + j * 32);
            a[0][2 * j + 1] = *(const float4v*)(xrow + j * 32 + 4);
        }
        float4v acc[4] = {{0.f,0.f,0.f,0.f},{0.f,0.f,0.f,0.f},
                          {0.f,0.f,0.f,0.f},{0.f,0.f,0.f,0.f}};
#pragma unroll
        for (int c = 0; c < 4; ++c) {
            const int cb = c & 1, nb2 = cb ^ 1;
            if (c < 3) {
#pragma unroll
                for (int j = 0; j < 4; ++j) {        // prefetch chunk c+1
                    int kt = (c + 1) * 4 + j;
                    a[nb2][2 * j]     = *(const float4v*)(xrow + kt * 32);
                    a[nb2][2 * j + 1] = *(const float4v*)(xrow + kt * 32 + 4);
                }
            }
#pragma unroll
            for (int j = 0; j < 4; ++j) {            // compute chunk c
                int kt = c * 4 + j;
                union { short8 s8; unsigned short us[8]; } af;
                float4v lo = a[cb][2 * j], hi = a[cb][2 * j + 1];
                af.us[0] = f2bf(lo.x); af.us[1] = f2bf(lo.y);
                af.us[2] = f2bf(lo.z); af.us[3] = f2bf(lo.w);
                af.us[4] = f2bf(hi.x); af.us[5] = f2bf(hi.y);
                af.us[6] = f2bf(hi.z); af.us[7] = f2bf(hi.w);
#pragma unroll
                for (int ct = 0; ct < 4; ++ct) {
                    short8 bf = Wlds[kt * 4 + ct][lane];
                    acc[ct] = __builtin_amdgcn_mfma_f32_16x16x32_bf16(af.s8, bf, acc[ct], 0, 0, 0);
                }
            }
        }
#pragma unroll
        for (int reg = 0; reg < 4; ++reg) {
            int orow = r0 + quad * 4 + reg;
            float dinv = rsqrtf((float)(degi[orow] + 1));
#pragma unroll
            for (int ct = 0; ct < 4; ++ct)
                h[(size_t)orow * OUT_DIM + ct * 16 + l16] = f2bf(acc[ct][reg] * dinv);
        }
    }
}

// ---------------- gather + bias + log_softmax, one wave per node ----------------
// lane layout: half = lane>>5, c = lane&31; each ushort2 load instruction
// fetches TWO h rows (256 B); halves combined with one shfl_xor(32).
__global__ __launch_bounds__(256) void k_gather(const int* __restrict__ degi,
                                                const int* __restrict__ row_ptr,
                                                const int* __restrict__ csr,
                                                const unsigned short* __restrict__ h,
                                                const float* __restrict__ b,
                                                float* __restrict__ out) {
    int node = blockIdx.x * 4 + (threadIdx.x >> 6);
    int lane = threadIdx.x & 63;
    if (node >= N_NODES) return;
    const int half = lane >> 5, c = lane & 31;
    int cnt  = __builtin_amdgcn_readfirstlane(degi[node]);
    int base = __builtin_amdgcn_readfirstlane(row_ptr[node]);
    const unsigned int* h2 = (const unsigned int*)h;   // row i at h2[i*32 + c]

    float ax = 0.f, ay = 0.f;
    if (half == 0) {   // self-loop term
        unsigned int u = h2[(size_t)node * 32 + c];
        ax = __uint_as_float(u << 16);
        ay = __uint_as_float(u & 0xFFFF0000u);
    }
    int e = 0;
    for (; e + 8 <= cnt; e += 8) {
        int i0 = csr[base + e + half + 0];
        int i1 = csr[base + e + half + 2];
        int i2 = csr[base + e + half + 4];
        int i3 = csr[base + e + half + 6];
        unsigned int u0 = h2[(size_t)i0 * 32 + c];
        unsigned int u1 = h2[(size_t)i1 * 32 + c];
        unsigned int u2 = h2[(size_t)i2 * 32 + c];
        unsigned int u3 = h2[(size_t)i3 * 32 + c];
        ax += __uint_as_float(u0 << 16) + __uint_as_float(u1 << 16)
            + __uint_as_float(u2 << 16) + __uint_as_float(u3 << 16);
        ay += __uint_as_float(u0 & 0xFFFF0000u) + __uint_as_float(u1 & 0xFFFF0000u)
            + __uint_as_float(u2 & 0xFFFF0000u) + __uint_as_float(u3 & 0xFFFF0000u);
    }
    for (; e + 2 <= cnt; e += 2) {
        int i = csr[base + e + half];
        unsigned int u = h2[(size_t)i * 32 + c];
        ax += __uint_as_float(u << 16);
        ay += __uint_as_float(u & 0xFFFF0000u);
    }
    if (e < cnt && half == 0) {   // odd last edge
        int i = csr[base + e];
        unsigned int u = h2[(size_t)i * 32 + c];
        ax += __uint_as_float(u << 16);
        ay += __uint_as_float(u & 0xFFFF0000u);
    }
    // combine halves
    ax += __shfl_xor(ax, 32, 64);
    ay += __shfl_xor(ay, 32, 64);

    float dinv = rsqrtf((float)(cnt + 1));
    float2 bb = *(const float2*)&b[2 * c];
    float vx = ax * dinv + bb.x;
    float vy = ay * dinv + bb.y;
    // log_softmax over 64 cols held as 32 lanes x 2 (duplicated across halves)
    float m = fmaxf(vx, vy);
#pragma unroll
    for (int off = 16; off > 0; off >>= 1) m = fmaxf(m, __shfl_xor(m, off, 64));
    float s = expf(vx - m) + expf(vy - m);
#pragma unroll
    for (int off = 16; off > 0; off >>= 1) s += __shfl_xor(s, off, 64);
    float ls = logf(s);
    if (half == 0) {
        float2 res = make_float2(vx - m - ls, vy - m - ls);
        *(float2*)&out[(size_t)node * OUT_DIM + 2 * c] = res;
    }
}

extern "C" void kernel_launch(void* const* d_in, const int* in_sizes, int n_in,
                              void* d_out, int out_size, void* d_ws, size_t ws_size,
                              hipStream_t stream) {
    const float* x  = (const float*)d_in[0];
    const int*   ei = (const int*)d_in[1];   // [2, E]: row 0 = src, row 1 = dst
    const float* W  = (const float*)d_in[2];
    const float* b  = (const float*)d_in[3];
    float* out = (float*)d_out;

    char* ws = (char*)d_ws;
    int*            degi       = (int*)(ws + 0);              // 400,000 B
    int*            row_ptr    = (int*)(ws + 400000);         // 400,000 B
    int*            blockHist  = (int*)(ws + 800000);         // 524,288 B  [NB][NPB]
    int*            blockStart = (int*)(ws + 1324288);        // 524,288 B  [NB][NPB]
    int*            bucketBase = (int*)(ws + 1848576);        // 4,100 B (pad to 4,352)
    unsigned short* Wswz       = (unsigned short*)(ws + 1852928);   // 65,536 B
    unsigned short* h          = (unsigned short*)(ws + 1918464);   // 12,800,000 B
    int*            parts      = (int*)(ws + 14718464);       // 6,400,000 B
    int*            csr        = (int*)(ws + 21118464);       // 6,400,000 B

    const int* src = ei;
    const int* dst = ei + N_EDGES;

    k_hist1    <<<NPB, 256,  0, stream>>>(dst, blockHist);
    k_offsets  <<<1,   1024, 0, stream>>>(blockHist, blockStart, bucketBase);
    k_partition<<<NPB, 256,  0, stream>>>(dst, src, blockStart, parts);
    k_bucket   <<<N_BUCKETS_USED, 256, 0, stream>>>(parts, bucketBase, degi, row_ptr, csr);
    k_wswz     <<<(IN_DIM * OUT_DIM + 255) / 256, 256, 0, stream>>>(W, Wswz);
    k_gemm     <<<512, 512, 0, stream>>>(x, Wswz, degi, h);
    k_gather   <<<(N_NODES + 3) / 4, 256, 0, stream>>>(degi, row_ptr, csr, h, b, out);
}